// Round 2
// baseline (405.697 us; speedup 1.0000x reference)
//
#include <hip/hip_runtime.h>
#include <hip/hip_bf16.h>

typedef __bf16 bf16x8 __attribute__((ext_vector_type(8)));
typedef float  f32x4  __attribute__((ext_vector_type(4)));

#define B_ROWS 65536
#define MR 16            // rows (images) per block; LDS 31.2KB -> 5 blocks/CU (20 waves)
#define H0S 712          // h0 stride bf16 (704+8 pad: 1424B -> row start bank 4r, 2/bank on b128)
#define H1S 264          // h1 stride (256+8: 528B -> bank 4r)
#define H2S 136          // h2 stride (128+8: 272B -> bank 4r)
#define KC1 22           // 704/32
#define KC2 8            // 256/32
#define KC3 4            // 128/32

#define W1B_ELEMS (704*256)
#define W2B_ELEMS (256*128)
#define W3B_ELEMS (128*16)

// Pack weights to bf16 in MFMA-B layout [kc][n][ki(32)]: a lane's 8 k-values
// (ki = (lane>>4)*8 + j) are 16B-contiguous.
__global__ void pack_weights(const float* __restrict__ w1,
                             const float* __restrict__ w2,
                             const float* __restrict__ w3,
                             __hip_bfloat16* __restrict__ w1b,
                             __hip_bfloat16* __restrict__ w2b,
                             __hip_bfloat16* __restrict__ w3b) {
    int idx = blockIdx.x * 256 + threadIdx.x;
    if (idx < W1B_ELEMS) {
        int ki = idx & 31, t = idx >> 5;
        int n = t & 255, kc = t >> 8;
        int k = kc * 32 + ki;
        float v = (k < 676) ? w1[k * 256 + n] : 0.0f;   // zero-pad K 676->704
        w1b[idx] = __float2bfloat16(v);
    } else if (idx < W1B_ELEMS + W2B_ELEMS) {
        int j = idx - W1B_ELEMS;
        int ki = j & 31, t = j >> 5;
        int n = t & 127, kc = t >> 7;
        w2b[j] = __float2bfloat16(w2[(kc * 32 + ki) * 128 + n]);
    } else if (idx < W1B_ELEMS + W2B_ELEMS + W3B_ELEMS) {
        int j = idx - W1B_ELEMS - W2B_ELEMS;
        int ki = j & 31, t = j >> 5;
        int n = t & 15, kc = t >> 4;
        float v = (n < 10) ? w3[(kc * 32 + ki) * 10 + n] : 0.0f;  // zero-pad N 10->16
        w3b[j] = __float2bfloat16(v);
    }
}

// Fused conv3x3(valid) + 676->256 relu + 256->128 relu + 128->10.
// MR=16 rows/block, 256 threads (4 waves). LDS 31232B -> 5 blocks/CU, ~62% occ.
__global__ __launch_bounds__(256, 5)
void fused_model(const float* __restrict__ x, const float* __restrict__ cw,
                 const __hip_bfloat16* __restrict__ w1b, const float* __restrict__ b1,
                 const __hip_bfloat16* __restrict__ w2b, const float* __restrict__ b2,
                 const __hip_bfloat16* __restrict__ w3b, const float* __restrict__ b3,
                 float* __restrict__ out) {
    // LDS: [h0: 16*712*2 = 22784][h1: 16*264*2 = 8448] = 31232B. h2 overlays dead h0.
    __shared__ __align__(16) char smem[MR * H0S * 2 + MR * H1S * 2];
    __hip_bfloat16* h0s = (__hip_bfloat16*)smem;
    __hip_bfloat16* h1s = (__hip_bfloat16*)(smem + MR * H0S * 2);
    __hip_bfloat16* h2s = (__hip_bfloat16*)smem;

    const int tid = threadIdx.x;
    const int r0  = blockIdx.x * MR;

    const float c00 = cw[0], c01 = cw[1], c02 = cw[2];
    const float c10 = cw[3], c11 = cw[4], c12 = cw[5];
    const float c20 = cw[6], c21 = cw[7], c22 = cw[8];

    // ---- Stage 1: conv (fp32 exact), h0[r][i*26+j] -> LDS bf16 ----
    // One task = (image r, output row i). The 3 needed input rows are 84
    // CONTIGUOUS floats -> issue 21 back-to-back float4 loads, then compute.
    for (int t = tid; t < MR * 26; t += 256) {
        int r = t / 26;
        int i = t - r * 26;
        const float4* p4 = (const float4*)(x + (size_t)(r0 + r) * 784 + i * 28);
        union { float4 v4[21]; float f[84]; } u;
        #pragma unroll
        for (int q = 0; q < 21; q++) u.v4[q] = p4[q];   // one burst, one vmcnt wait
        __hip_bfloat16* hp = h0s + r * H0S + i * 26;
        #pragma unroll
        for (int j = 0; j < 26; j += 2) {
            float a0 = c00*u.f[j]    + c01*u.f[j+1]  + c02*u.f[j+2]
                     + c10*u.f[28+j] + c11*u.f[29+j] + c12*u.f[30+j]
                     + c20*u.f[56+j] + c21*u.f[57+j] + c22*u.f[58+j];
            float a1 = c00*u.f[j+1]  + c01*u.f[j+2]  + c02*u.f[j+3]
                     + c10*u.f[29+j] + c11*u.f[30+j] + c12*u.f[31+j]
                     + c20*u.f[57+j] + c21*u.f[58+j] + c22*u.f[59+j];
            __hip_bfloat162 p;
            p.x = __float2bfloat16(a0);
            p.y = __float2bfloat16(a1);
            *(__hip_bfloat162*)(hp + j) = p;            // 4B-aligned (52i+2j bytes)
        }
    }
    // zero K-pad cols 676..703 (704..711 are never read by MFMA)
    for (int t = tid; t < MR * 28; t += 256) {
        int r = t / 28;
        int c = 676 + (t - r * 28);
        h0s[r * H0S + c] = __float2bfloat16(0.0f);
    }
    __syncthreads();

    const int wave = tid >> 6;
    const int lane = tid & 63;
    const int l15  = lane & 15;
    const int g    = lane >> 4;

    // ---- Stage 2: GEMM1  h1 = relu(h0 @ w1 + b1), M=16 N=256 K=704 ----
    {
        f32x4 acc[4];
        #pragma unroll
        for (int nt = 0; nt < 4; nt++) acc[nt] = (f32x4){0.f, 0.f, 0.f, 0.f};
        const int nb = wave * 64;
        const __hip_bfloat16* bbase = w1b + ((size_t)(nb + l15) * 32 + g * 8);
        // software pipeline: prefetch B(kc+1) + A(kc+1) during MFMA(kc)
        bf16x8 bcur[4], acur;
        #pragma unroll
        for (int nt = 0; nt < 4; nt++)
            bcur[nt] = *(const bf16x8*)(bbase + nt * (16 * 32));
        acur = *(const bf16x8*)(h0s + l15 * H0S + g * 8);
        for (int kc = 0; kc < KC1; kc++) {
            bf16x8 bnext[4], anext;
            if (kc + 1 < KC1) {
                const __hip_bfloat16* bp = bbase + (size_t)(kc + 1) * (256 * 32);
                #pragma unroll
                for (int nt = 0; nt < 4; nt++)
                    bnext[nt] = *(const bf16x8*)(bp + nt * (16 * 32));
                anext = *(const bf16x8*)(h0s + l15 * H0S + (kc + 1) * 32 + g * 8);
            }
            #pragma unroll
            for (int nt = 0; nt < 4; nt++)
                acc[nt] = __builtin_amdgcn_mfma_f32_16x16x32_bf16(
                    acur, bcur[nt], acc[nt], 0, 0, 0);
            if (kc + 1 < KC1) {
                #pragma unroll
                for (int nt = 0; nt < 4; nt++) bcur[nt] = bnext[nt];
                acur = anext;
            }
        }
        #pragma unroll
        for (int nt = 0; nt < 4; nt++) {
            const int n = nb + nt * 16 + l15;
            const float bias = b1[n];
            #pragma unroll
            for (int q = 0; q < 4; q++) {
                const int row = g * 4 + q;   // C/D: col=lane&15, row=(lane>>4)*4+q
                float v = acc[nt][q] + bias;
                h1s[row * H1S + n] = __float2bfloat16(fmaxf(v, 0.0f));
            }
        }
    }
    __syncthreads();

    // ---- Stage 3: GEMM2  h2 = relu(h1 @ w2 + b2), M=16 N=128 K=256 ----
    {
        f32x4 acc[2];
        acc[0] = (f32x4){0.f, 0.f, 0.f, 0.f};
        acc[1] = (f32x4){0.f, 0.f, 0.f, 0.f};
        const int nb = wave * 32;
        #pragma unroll
        for (int kc = 0; kc < KC2; kc++) {
            bf16x8 a = *(const bf16x8*)(h1s + l15 * H1S + kc * 32 + g * 8);
            bf16x8 b0 = *(const bf16x8*)(w2b + (((size_t)kc * 128 + nb + l15) * 32 + g * 8));
            bf16x8 b1v = *(const bf16x8*)(w2b + (((size_t)kc * 128 + nb + 16 + l15) * 32 + g * 8));
            acc[0] = __builtin_amdgcn_mfma_f32_16x16x32_bf16(a, b0, acc[0], 0, 0, 0);
            acc[1] = __builtin_amdgcn_mfma_f32_16x16x32_bf16(a, b1v, acc[1], 0, 0, 0);
        }
        #pragma unroll
        for (int nt = 0; nt < 2; nt++) {
            const int n = nb + nt * 16 + l15;
            const float bias = b2[n];
            #pragma unroll
            for (int q = 0; q < 4; q++) {
                const int row = g * 4 + q;
                float v = acc[nt][q] + bias;
                h2s[row * H2S + n] = __float2bfloat16(fmaxf(v, 0.0f));  // overlays dead h0
            }
        }
    }
    __syncthreads();

    // ---- Stage 4: GEMM3  out = h2 @ w3 + b3, M=16 N=16(10) K=128 ----
    if (wave == 0) {
        f32x4 acc3 = (f32x4){0.f, 0.f, 0.f, 0.f};
        #pragma unroll
        for (int kc = 0; kc < KC3; kc++) {
            bf16x8 a = *(const bf16x8*)(h2s + l15 * H2S + kc * 32 + g * 8);
            bf16x8 b = *(const bf16x8*)(w3b + (((size_t)kc * 16 + l15) * 32 + g * 8));
            acc3 = __builtin_amdgcn_mfma_f32_16x16x32_bf16(a, b, acc3, 0, 0, 0);
        }
        if (l15 < 10) {
            const float bias = b3[l15];
            #pragma unroll
            for (int q = 0; q < 4; q++) {
                const int row = g * 4 + q;
                out[(size_t)(r0 + row) * 10 + l15] = acc3[q] + bias;
            }
        }
    }
}

extern "C" void kernel_launch(void* const* d_in, const int* in_sizes, int n_in,
                              void* d_out, int out_size, void* d_ws, size_t ws_size,
                              hipStream_t stream) {
    const float* x  = (const float*)d_in[0];
    const float* cw = (const float*)d_in[1];
    const float* w1 = (const float*)d_in[2];
    const float* b1 = (const float*)d_in[3];
    const float* w2 = (const float*)d_in[4];
    const float* b2 = (const float*)d_in[5];
    const float* w3 = (const float*)d_in[6];
    const float* b3 = (const float*)d_in[7];
    float* out = (float*)d_out;

    __hip_bfloat16* w1b = (__hip_bfloat16*)d_ws;
    __hip_bfloat16* w2b = w1b + W1B_ELEMS;
    __hip_bfloat16* w3b = w2b + W2B_ELEMS;

    const int pack_total = W1B_ELEMS + W2B_ELEMS + W3B_ELEMS;  // 215040
    pack_weights<<<(pack_total + 255) / 256, 256, 0, stream>>>(w1, w2, w3, w1b, w2b, w3b);
    fused_model<<<B_ROWS / MR, 256, 0, stream>>>(x, cw, w1b, b1, w2b, b2, w3b, b3, out);
}

// Round 3
// 390.914 us; speedup vs baseline: 1.0378x; 1.0378x over previous
//
#include <hip/hip_runtime.h>
#include <hip/hip_bf16.h>

typedef __bf16 bf16x8 __attribute__((ext_vector_type(8)));
typedef float  f32x4  __attribute__((ext_vector_type(4)));

#define B_ROWS 65536
#define MR 16            // rows (images) per block; LDS 31.2KB -> 4 blocks/CU (16 waves, 50%)
#define H0S 712          // h0 stride bf16 (704+8 pad)
#define H1S 264          // h1 stride (256+8 pad)
#define H2S 136          // h2 stride (128+8 pad)
#define KC1 22           // 704/32
#define KC2 8            // 256/32
#define KC3 4            // 128/32

#define W1B_ELEMS (704*256)
#define W2B_ELEMS (256*128)
#define W3B_ELEMS (128*16)

// Pack weights to bf16 in MFMA-B layout [kc][n][ki(32)]: a lane's 8 k-values
// (ki = (lane>>4)*8 + j) are 16B-contiguous.
__global__ void pack_weights(const float* __restrict__ w1,
                             const float* __restrict__ w2,
                             const float* __restrict__ w3,
                             __hip_bfloat16* __restrict__ w1b,
                             __hip_bfloat16* __restrict__ w2b,
                             __hip_bfloat16* __restrict__ w3b) {
    int idx = blockIdx.x * 256 + threadIdx.x;
    if (idx < W1B_ELEMS) {
        int ki = idx & 31, t = idx >> 5;
        int n = t & 255, kc = t >> 8;
        int k = kc * 32 + ki;
        float v = (k < 676) ? w1[k * 256 + n] : 0.0f;   // zero-pad K 676->704
        w1b[idx] = __float2bfloat16(v);
    } else if (idx < W1B_ELEMS + W2B_ELEMS) {
        int j = idx - W1B_ELEMS;
        int ki = j & 31, t = j >> 5;
        int n = t & 127, kc = t >> 7;
        w2b[j] = __float2bfloat16(w2[(kc * 32 + ki) * 128 + n]);
    } else if (idx < W1B_ELEMS + W2B_ELEMS + W3B_ELEMS) {
        int j = idx - W1B_ELEMS - W2B_ELEMS;
        int ki = j & 31, t = j >> 5;
        int n = t & 15, kc = t >> 4;
        float v = (n < 10) ? w3[(kc * 32 + ki) * 10 + n] : 0.0f;  // zero-pad N 10->16
        w3b[j] = __float2bfloat16(v);
    }
}

// Fused conv3x3(valid) + 676->256 relu + 256->128 relu + 128->10.
// MR=16 rows/block, 256 threads (4 waves).
// launch_bounds(256,4): 128-VGPR cap -> conv working set (~70 live) does NOT
// spill (round-2's (256,5) capped at 48 VGPR -> 12MB scratch WRITE_SIZE, -20%).
__global__ __launch_bounds__(256, 4)
void fused_model(const float* __restrict__ x, const float* __restrict__ cw,
                 const __hip_bfloat16* __restrict__ w1b, const float* __restrict__ b1,
                 const __hip_bfloat16* __restrict__ w2b, const float* __restrict__ b2,
                 const __hip_bfloat16* __restrict__ w3b, const float* __restrict__ b3,
                 float* __restrict__ out) {
    // LDS: [h0: 16*712*2 = 22784][h1: 16*264*2 = 8448] = 31232B. h2 overlays dead h0.
    __shared__ __align__(16) char smem[MR * H0S * 2 + MR * H1S * 2];
    __hip_bfloat16* h0s = (__hip_bfloat16*)smem;
    __hip_bfloat16* h1s = (__hip_bfloat16*)(smem + MR * H0S * 2);
    __hip_bfloat16* h2s = (__hip_bfloat16*)smem;

    const int tid = threadIdx.x;
    const int r0  = blockIdx.x * MR;

    const float c00 = cw[0], c01 = cw[1], c02 = cw[2];
    const float c10 = cw[3], c11 = cw[4], c12 = cw[5];
    const float c20 = cw[6], c21 = cw[7], c22 = cw[8];

    // ---- Stage 1: conv (fp32 exact), h0[r][i*26+j] -> LDS bf16 ----
    // Task = (image r, out row i, half j0∈{0,13}): 13 outputs from a 3x15
    // window. 12 independent float4 loads issued up-front -> ONE vmcnt wait.
    // Live regs ~70: no spill under the 128 cap.
    for (int t = tid; t < MR * 52; t += 256) {
        int r = t / 52;
        int q = t - r * 52;
        int i = q >> 1;
        int j0 = (q & 1) * 13;
        int s = j0 ? 12 : 0;                 // first loaded col (float4-aligned)
        union { float4 v4[12]; float f[48]; } u;
        #pragma unroll
        for (int di = 0; di < 3; di++) {
            const float4* p = (const float4*)(x + (size_t)(r0 + r) * 784 + (i + di) * 28 + s);
            u.v4[di * 4 + 0] = p[0];
            u.v4[di * 4 + 1] = p[1];
            u.v4[di * 4 + 2] = p[2];
            u.v4[di * 4 + 3] = p[3];
        }
        const int o = j0 ? 1 : 0;            // j0 - s
        __hip_bfloat16* hp = h0s + r * H0S + i * 26 + j0;
        #pragma unroll
        for (int jj = 0; jj < 13; jj++) {
            const int b = jj + o;
            float a = c00 * u.f[b]      + c01 * u.f[b + 1]  + c02 * u.f[b + 2]
                    + c10 * u.f[16 + b] + c11 * u.f[17 + b] + c12 * u.f[18 + b]
                    + c20 * u.f[32 + b] + c21 * u.f[33 + b] + c22 * u.f[34 + b];
            hp[jj] = __float2bfloat16(a);
        }
    }
    // zero K-pad cols 676..703 (704..711 never read by MFMA)
    for (int t = tid; t < MR * 28; t += 256) {
        int r = t / 28;
        int c = 676 + (t - r * 28);
        h0s[r * H0S + c] = __float2bfloat16(0.0f);
    }

    const int wave = tid >> 6;
    const int lane = tid & 63;
    const int l15  = lane & 15;
    const int g    = lane >> 4;

    // ---- Stage 2: GEMM1  h1 = relu(h0 @ w1 + b1), M=16 N=256 K=704 ----
    {
        const int nb = wave * 64;
        const __hip_bfloat16* bbase = w1b + ((size_t)(nb + l15) * 32 + g * 8);
        // Prefetch B(kc=0) BEFORE the barrier: independent of conv output,
        // flies during the conv tail.
        bf16x8 bcur[4];
        #pragma unroll
        for (int nt = 0; nt < 4; nt++)
            bcur[nt] = *(const bf16x8*)(bbase + nt * (16 * 32));
        __syncthreads();

        f32x4 acc[4];
        #pragma unroll
        for (int nt = 0; nt < 4; nt++) acc[nt] = (f32x4){0.f, 0.f, 0.f, 0.f};
        bf16x8 acur = *(const bf16x8*)(h0s + l15 * H0S + g * 8);
        for (int kc = 0; kc < KC1; kc++) {
            bf16x8 bnext[4], anext;
            if (kc + 1 < KC1) {
                const __hip_bfloat16* bp = bbase + (size_t)(kc + 1) * (256 * 32);
                #pragma unroll
                for (int nt = 0; nt < 4; nt++)
                    bnext[nt] = *(const bf16x8*)(bp + nt * (16 * 32));
                anext = *(const bf16x8*)(h0s + l15 * H0S + (kc + 1) * 32 + g * 8);
            }
            #pragma unroll
            for (int nt = 0; nt < 4; nt++)
                acc[nt] = __builtin_amdgcn_mfma_f32_16x16x32_bf16(
                    acur, bcur[nt], acc[nt], 0, 0, 0);
            if (kc + 1 < KC1) {
                #pragma unroll
                for (int nt = 0; nt < 4; nt++) bcur[nt] = bnext[nt];
                acur = anext;
            }
        }
        #pragma unroll
        for (int nt = 0; nt < 4; nt++) {
            const int n = nb + nt * 16 + l15;
            const float bias = b1[n];
            #pragma unroll
            for (int q = 0; q < 4; q++) {
                const int row = g * 4 + q;   // C/D: col=lane&15, row=(lane>>4)*4+q
                float v = acc[nt][q] + bias;
                h1s[row * H1S + n] = __float2bfloat16(fmaxf(v, 0.0f));
            }
        }
    }
    __syncthreads();

    // ---- Stage 3: GEMM2  h2 = relu(h1 @ w2 + b2), M=16 N=128 K=256 ----
    {
        f32x4 acc[2];
        acc[0] = (f32x4){0.f, 0.f, 0.f, 0.f};
        acc[1] = (f32x4){0.f, 0.f, 0.f, 0.f};
        const int nb = wave * 32;
        #pragma unroll
        for (int kc = 0; kc < KC2; kc++) {
            bf16x8 a  = *(const bf16x8*)(h1s + l15 * H1S + kc * 32 + g * 8);
            bf16x8 b0 = *(const bf16x8*)(w2b + (((size_t)kc * 128 + nb + l15) * 32 + g * 8));
            bf16x8 b1v = *(const bf16x8*)(w2b + (((size_t)kc * 128 + nb + 16 + l15) * 32 + g * 8));
            acc[0] = __builtin_amdgcn_mfma_f32_16x16x32_bf16(a, b0, acc[0], 0, 0, 0);
            acc[1] = __builtin_amdgcn_mfma_f32_16x16x32_bf16(a, b1v, acc[1], 0, 0, 0);
        }
        #pragma unroll
        for (int nt = 0; nt < 2; nt++) {
            const int n = nb + nt * 16 + l15;
            const float bias = b2[n];
            #pragma unroll
            for (int q = 0; q < 4; q++) {
                const int row = g * 4 + q;
                float v = acc[nt][q] + bias;
                h2s[row * H2S + n] = __float2bfloat16(fmaxf(v, 0.0f));  // overlays dead h0
            }
        }
    }
    __syncthreads();

    // ---- Stage 4: GEMM3  out = h2 @ w3 + b3, M=16 N=16(10) K=128 ----
    if (wave == 0) {
        f32x4 acc3 = (f32x4){0.f, 0.f, 0.f, 0.f};
        #pragma unroll
        for (int kc = 0; kc < KC3; kc++) {
            bf16x8 a = *(const bf16x8*)(h2s + l15 * H2S + kc * 32 + g * 8);
            bf16x8 b = *(const bf16x8*)(w3b + (((size_t)kc * 16 + l15) * 32 + g * 8));
            acc3 = __builtin_amdgcn_mfma_f32_16x16x32_bf16(a, b, acc3, 0, 0, 0);
        }
        if (l15 < 10) {
            const float bias = b3[l15];
            #pragma unroll
            for (int q = 0; q < 4; q++) {
                const int row = g * 4 + q;
                out[(size_t)(r0 + row) * 10 + l15] = acc3[q] + bias;
            }
        }
    }
}

extern "C" void kernel_launch(void* const* d_in, const int* in_sizes, int n_in,
                              void* d_out, int out_size, void* d_ws, size_t ws_size,
                              hipStream_t stream) {
    const float* x  = (const float*)d_in[0];
    const float* cw = (const float*)d_in[1];
    const float* w1 = (const float*)d_in[2];
    const float* b1 = (const float*)d_in[3];
    const float* w2 = (const float*)d_in[4];
    const float* b2 = (const float*)d_in[5];
    const float* w3 = (const float*)d_in[6];
    const float* b3 = (const float*)d_in[7];
    float* out = (float*)d_out;

    __hip_bfloat16* w1b = (__hip_bfloat16*)d_ws;
    __hip_bfloat16* w2b = w1b + W1B_ELEMS;
    __hip_bfloat16* w3b = w2b + W2B_ELEMS;

    const int pack_total = W1B_ELEMS + W2B_ELEMS + W3B_ELEMS;  // 215040
    pack_weights<<<(pack_total + 255) / 256, 256, 0, stream>>>(w1, w2, w3, w1b, w2b, w3b);
    fused_model<<<B_ROWS / MR, 256, 0, stream>>>(x, cw, w1b, b1, w2b, b2, w3b, b3, out);
}